// Round 4
// baseline (413.634 us; speedup 1.0000x reference)
//
#include <hip/hip_runtime.h>
#include <hip/hip_bf16.h>
#include <hip/hip_fp16.h>

// 5-layer GCN: out = relu( D^-1/2 (A+I) D^-1/2 (x W_l) + b_l ), x5.
// N=50000, E=800000, D=128.
//
// R19: widen gathers. R16-R18 all ~44us regardless of VALU count or
// load scheduling -> agg is VMEM-front-end (TA) instruction-bound:
// each dword gather = 64 addresses of TA work, 20 VMEM insts / 16
// edges. New mapping: 8-lane node group = 4 edge slots x 2 feature
// halves; each lane gathers uint4 (16B, 8 feats) of its edge's 32B
// row. 3 VMEM insts / 8 edges (1 dwordx2 edat + 2 uint4 gathers).
// Same bytes, same L2 line traffic, 1/3 the VMEM instructions.
// End: __shfl_xor(2,4) reduce over edge slots, s4==0 lanes store.
// Everything else frozen at R17/R18 (dinv folded in GEMM, edat=src<<5,
// slice-major h, slice = blockIdx&7).

#define GCN_DIM 128

typedef short bf16x8 __attribute__((ext_vector_type(8)));
typedef float f32x4 __attribute__((ext_vector_type(4)));
typedef unsigned int u32x4 __attribute__((ext_vector_type(4)));

__device__ __forceinline__ unsigned short f2bf(float f) {
    unsigned int u = __float_as_uint(f);
    u += 0x7FFFu + ((u >> 16) & 1u);  // RTNE
    return (unsigned short)(u >> 16);
}
__device__ __forceinline__ float bf2f(unsigned short b) {
    return __uint_as_float(((unsigned int)b) << 16);
}
__device__ __forceinline__ float bflo(unsigned int p) { return __uint_as_float(p << 16); }
__device__ __forceinline__ float bfhi(unsigned int p) { return __uint_as_float(p & 0xFFFF0000u); }

// count + capture per-edge rank (old value of the atomic)
__global__ void count_kernel(const int* __restrict__ dst, int* __restrict__ cnt,
                             int* __restrict__ rank, int E) {
    int e = blockIdx.x * 256 + threadIdx.x;
    if (e < E) rank[e] = atomicAdd(&cnt[dst[e]], 1);
}

// ---- hierarchical scan ----
__global__ __launch_bounds__(256) void scan_part_kernel(const int* __restrict__ cnt,
                                                        int* __restrict__ loc,
                                                        int* __restrict__ bsum, int n) {
    __shared__ int s[256];
    int t = threadIdx.x;
    int i0 = blockIdx.x * 1024 + t * 4;
    int v0 = (i0 + 0 < n) ? cnt[i0 + 0] : 0;
    int v1 = (i0 + 1 < n) ? cnt[i0 + 1] : 0;
    int v2 = (i0 + 2 < n) ? cnt[i0 + 2] : 0;
    int v3 = (i0 + 3 < n) ? cnt[i0 + 3] : 0;
    int tsum = v0 + v1 + v2 + v3;
    s[t] = tsum;
    __syncthreads();
    for (int d = 1; d < 256; d <<= 1) {
        int u = (t >= d) ? s[t - d] : 0;
        __syncthreads();
        s[t] += u;
        __syncthreads();
    }
    int base = s[t] - tsum;
    if (i0 + 0 < n) loc[i0 + 0] = base; base += v0;
    if (i0 + 1 < n) loc[i0 + 1] = base; base += v1;
    if (i0 + 2 < n) loc[i0 + 2] = base; base += v2;
    if (i0 + 3 < n) loc[i0 + 3] = base;
    if (t == 255) bsum[blockIdx.x] = s[255];
}

__global__ __launch_bounds__(256) void scan_top_kernel(int* __restrict__ bsum, int nb) {
    __shared__ int s[256];
    int t = threadIdx.x;
    int v = (t < nb) ? bsum[t] : 0;
    s[t] = v;
    __syncthreads();
    for (int d = 1; d < 256; d <<= 1) {
        int u = (t >= d) ? s[t - d] : 0;
        __syncthreads();
        s[t] += u;
        __syncthreads();
    }
    if (t < nb) bsum[t] = s[t] - v;
}

// scan finalize + dinv (folded)
__global__ void scan_add_kernel(int* __restrict__ offs,
                                const int* __restrict__ bsum, const int* __restrict__ cnt,
                                float* __restrict__ dinv, int n, int E) {
    int i = blockIdx.x * 256 + threadIdx.x;
    if (i < n) {
        offs[i] = offs[i] + bsum[i >> 10];
        dinv[i] = rsqrtf((float)cnt[i] + 1.0f);
    }
    if (i == 0) offs[n] = E;
}

// CSR fill, atomic-free: p = offs[dst] + rank[e].
// edat = src*32: the byte offset of src's 32B feature row within a slice.
__global__ void fill_kernel(const int* __restrict__ src, const int* __restrict__ dst,
                            const int* __restrict__ rank, const int* __restrict__ offs,
                            unsigned int* __restrict__ edat, int E) {
    int e = blockIdx.x * 256 + threadIdx.x;
    if (e < E) {
        int d = dst[e];
        int p = offs[d] + rank[e];
        edat[p] = ((unsigned int)src[e]) << 5;
    }
}

// x0 fp32 -> (xh, xl) bf16 pair.
__global__ void split_x_kernel(const float* __restrict__ x, unsigned short* __restrict__ xh,
                               unsigned short* __restrict__ xl, int total) {
    int i = (blockIdx.x * 256 + threadIdx.x) * 4;
    if (i >= total) return;
    float4 v = *(const float4*)&x[i];
    ushort4 h4, l4;
    h4.x = f2bf(v.x); l4.x = f2bf(v.x - bf2f(h4.x));
    h4.y = f2bf(v.y); l4.y = f2bf(v.y - bf2f(h4.y));
    h4.z = f2bf(v.z); l4.z = f2bf(v.z - bf2f(h4.z));
    h4.w = f2bf(v.w); l4.w = f2bf(v.w - bf2f(h4.w));
    *(ushort4*)&xh[i] = h4;
    *(ushort4*)&xl[i] = l4;
}

// W [l][k][n] fp32 -> Wfh/Wfl in MFMA fragment order:
// group g = l*32 + t*4 + ks; elem = ((g*64) + q*16+ln)*8 + j
// holds W^T[t*16+ln][ks*32+q*8+j].  (Used as the A operand.)
__global__ void wsplit_kernel(const float* __restrict__ Wall, unsigned short* __restrict__ Wfh,
                              unsigned short* __restrict__ Wfl, int total) {
    int idx = blockIdx.x * 256 + threadIdx.x;
    if (idx >= total) return;
    int l = idx >> 14;
    int rem = idx & 16383;
    int k = rem >> 7;
    int nn = rem & 127;
    float v = Wall[idx];
    unsigned short hi = f2bf(v);
    unsigned short lo = f2bf(v - bf2f(hi));
    int t = nn >> 4, ln = nn & 15;
    int ks = k >> 5, q = (k >> 3) & 3, j = k & 7;
    int o = ((((l << 5) | (t << 2) | ks) << 6) | (q << 4) | ln) * 8 + j;
    Wfh[o] = hi;
    Wfl[o] = lo;
}

// MFMA GEMM: h = ((xh+xl) @ (Wh+Wl)) * dinv[row], bf16 SLICE-MAJOR store
// h[(t*N + node)*16 + q*4]. 64 rows/block, 4 waves x 1 m-tile, t-pairs.
// dinv[row] folded here so agg needs no per-edge weight (R17).
__global__ __launch_bounds__(256) void gemm_mfma_kernel(
    const unsigned short* __restrict__ xh, const unsigned short* __restrict__ xl,
    const unsigned short* __restrict__ Wfh, const unsigned short* __restrict__ Wfl,
    const float* __restrict__ dinv,
    unsigned short* __restrict__ h, int n) {
    __shared__ unsigned short ldsW[2][8192];  // 16KB hi + 16KB lo
    int tid = threadIdx.x;
    int wave = tid >> 6, lane = tid & 63;
    int q = lane >> 4, ln = lane & 15;
    int rowbase = blockIdx.x * 64 + wave * 16;
    bf16x8 A[4][2];  // x fragments (B operand): [ks][hi/lo]
    {
        int ar = rowbase + ln;
        if (ar >= n) ar = n - 1;
        size_t base = (size_t)ar * GCN_DIM;
#pragma unroll
        for (int ks = 0; ks < 4; ks++) {
            A[ks][0] = *(const bf16x8*)&xh[base + ks * 32 + q * 8];
            A[ks][1] = *(const bf16x8*)&xl[base + ks * 32 + q * 8];
        }
    }
    int node = rowbase + ln;
    float di = (node < n) ? dinv[node] : 0.f;
#pragma unroll
    for (int half = 0; half < 2; half++) {
        if (half) __syncthreads();  // wait for previous half's compute
        {
            const uint4* gh = (const uint4*)(Wfh + half * 8192);
            const uint4* gl = (const uint4*)(Wfl + half * 8192);
            uint4* sh = (uint4*)ldsW[0];
            uint4* sl = (uint4*)ldsW[1];
#pragma unroll
            for (int r = 0; r < 4; r++) {
                sh[tid + 256 * r] = gh[tid + 256 * r];
                sl[tid + 256 * r] = gl[tid + 256 * r];
            }
        }
        __syncthreads();
#pragma unroll
        for (int tp = 0; tp < 2; tp++) {  // t-pair: tt_a = tp*2, tt_b = tp*2+1
            int tta = tp * 2, ttb = tp * 2 + 1;
            f32x4 accA = (f32x4)(0.f), accB = (f32x4)(0.f);
#pragma unroll
            for (int ks = 0; ks < 4; ks++) {
                int foA = ((tta * 4 + ks) * 64 + lane) * 8;
                int foB = ((ttb * 4 + ks) * 64 + lane) * 8;
                bf16x8 bhA = *(const bf16x8*)&ldsW[0][foA];
                bf16x8 blA = *(const bf16x8*)&ldsW[1][foA];
                bf16x8 bhB = *(const bf16x8*)&ldsW[0][foB];
                bf16x8 blB = *(const bf16x8*)&ldsW[1][foB];
                accA = __builtin_amdgcn_mfma_f32_16x16x32_bf16(bhA, A[ks][0], accA, 0, 0, 0);
                accB = __builtin_amdgcn_mfma_f32_16x16x32_bf16(bhB, A[ks][0], accB, 0, 0, 0);
                accA = __builtin_amdgcn_mfma_f32_16x16x32_bf16(bhA, A[ks][1], accA, 0, 0, 0);
                accB = __builtin_amdgcn_mfma_f32_16x16x32_bf16(bhB, A[ks][1], accB, 0, 0, 0);
                accA = __builtin_amdgcn_mfma_f32_16x16x32_bf16(blA, A[ks][0], accA, 0, 0, 0);
                accB = __builtin_amdgcn_mfma_f32_16x16x32_bf16(blB, A[ks][0], accB, 0, 0, 0);
            }
            if (node < n) {
                int ta = half * 4 + tta, tb = half * 4 + ttb;
                ushort4 oA, oB;
                oA.x = f2bf(accA[0] * di); oA.y = f2bf(accA[1] * di);
                oA.z = f2bf(accA[2] * di); oA.w = f2bf(accA[3] * di);
                oB.x = f2bf(accB[0] * di); oB.y = f2bf(accB[1] * di);
                oB.z = f2bf(accB[2] * di); oB.w = f2bf(accB[3] * di);
                *(ushort4*)&h[((size_t)ta * n + node) * 16 + q * 4] = oA;
                *(ushort4*)&h[((size_t)tb * n + node) * 16 + q * 4] = oB;
            }
        }
    }
}

// Sliced aggregation R19: 8 slices x 16 feats, slice-major h (pre-scaled
// by dinv[src] in the GEMM). Block = 32 nodes x one slice. Wave = 8 nodes
// x 8 lanes; lane = (edge slot s4 = ln>>1) x (feature half p = ln&1).
// Each lane gathers uint4 (16B = 8 feats) of its edge's 32B row ->
// 3 VMEM insts / 8 edges (dwordx2 edat + 2 uint4 gathers) vs 10 before.
// shfl_xor(2,4) reduce over edge slots; s4==0 lanes store 8 feats each.
__global__ __launch_bounds__(256) void agg_kernel(
    const unsigned short* __restrict__ h,
    const unsigned int* __restrict__ edat,
    const int* __restrict__ offs,
    const float* __restrict__ dinv, const float* __restrict__ bias,
    unsigned short* __restrict__ xh_out,
    unsigned short* __restrict__ xl_out,
    float* __restrict__ fout, int n) {
    int tid = threadIdx.x;
    int wave = tid >> 6, lane = tid & 63;
    int sub = lane >> 3, ln = lane & 7;
    int p  = ln & 1;   // feature half: 0 -> feats 0-7, 1 -> feats 8-15
    int s4 = ln >> 1;  // edge slot 0..3
    int slice = blockIdx.x & 7;
    int node = (blockIdx.x >> 3) * 32 + wave * 8 + sub;
    if (node >= n) return;
    const char* hs = (const char*)h + (size_t)slice * n * 32;  // slice base
    unsigned int p16 = (unsigned int)(p << 4);  // byte offset of feature half
    float di = dinv[node];
    float a0 = 0.f, a1 = 0.f, a2 = 0.f, a3 = 0.f;
    float a4 = 0.f, a5 = 0.f, a6 = 0.f, a7 = 0.f;
#define ACC8(g) do { \
        a0 += bflo((g).x); a1 += bfhi((g).x); \
        a2 += bflo((g).y); a3 += bfhi((g).y); \
        a4 += bflo((g).z); a5 += bfhi((g).z); \
        a6 += bflo((g).w); a7 += bfhi((g).w); } while (0)
    int s = offs[node], e = offs[node + 1];
    int j = s;
    // main: 8 edges / iter: 1 dwordx2 edat + 2 uint4 gathers per lane
    for (; j + 8 <= e; j += 8) {
        uint2 od = *(const uint2*)&edat[j + (s4 << 1)];  // this lane's 2 edges
        uint4 g0 = *(const uint4*)(hs + (od.x + p16));
        uint4 g1 = *(const uint4*)(hs + (od.y + p16));
        __builtin_amdgcn_sched_barrier(0);
        ACC8(g0);
        ACC8(g1);
    }
    if (j + 4 <= e) {
        unsigned int od = edat[j + s4];
        uint4 g0 = *(const uint4*)(hs + (od + p16));
        ACC8(g0);
        j += 4;
    }
    int rem = e - j;  // 0..3
    if (s4 < rem) {
        unsigned int od = edat[j + s4];
        uint4 g0 = *(const uint4*)(hs + (od + p16));
        ACC8(g0);
    }
    // reduce over edge slots (lanes differing in bits 1,2 of ln)
    a0 += __shfl_xor(a0, 2); a0 += __shfl_xor(a0, 4);
    a1 += __shfl_xor(a1, 2); a1 += __shfl_xor(a1, 4);
    a2 += __shfl_xor(a2, 2); a2 += __shfl_xor(a2, 4);
    a3 += __shfl_xor(a3, 2); a3 += __shfl_xor(a3, 4);
    a4 += __shfl_xor(a4, 2); a4 += __shfl_xor(a4, 4);
    a5 += __shfl_xor(a5, 2); a5 += __shfl_xor(a5, 4);
    a6 += __shfl_xor(a6, 2); a6 += __shfl_xor(a6, 4);
    a7 += __shfl_xor(a7, 2); a7 += __shfl_xor(a7, 4);
    // self term (once, after the reduce; every lane now holds the full sum)
    {
        uint4 sp4 = *(const uint4*)(hs + ((unsigned int)node * 32u + p16));
        ACC8(sp4);
    }
#undef ACC8
    if (s4 == 0) {
        int cg = slice * 16 + p * 8;  // global feature index of this lane's 8
        float4 b0 = *(const float4*)&bias[cg];
        float4 b1 = *(const float4*)&bias[cg + 4];
        float r0 = fmaxf(fmaf(di, a0, b0.x), 0.f);
        float r1 = fmaxf(fmaf(di, a1, b0.y), 0.f);
        float r2 = fmaxf(fmaf(di, a2, b0.z), 0.f);
        float r3 = fmaxf(fmaf(di, a3, b0.w), 0.f);
        float r4 = fmaxf(fmaf(di, a4, b1.x), 0.f);
        float r5 = fmaxf(fmaf(di, a5, b1.y), 0.f);
        float r6 = fmaxf(fmaf(di, a6, b1.z), 0.f);
        float r7 = fmaxf(fmaf(di, a7, b1.w), 0.f);
        if (fout) {
            f32x4 o0 = {r0, r1, r2, r3};
            f32x4 o1 = {r4, r5, r6, r7};
            float* fp = &fout[(size_t)node * GCN_DIM + cg];
            __builtin_nontemporal_store(o0, (f32x4*)fp);
            __builtin_nontemporal_store(o1, (f32x4*)(fp + 4));
        } else {
            unsigned short h0 = f2bf(r0), h1 = f2bf(r1), h2 = f2bf(r2), h3 = f2bf(r3);
            unsigned short h4 = f2bf(r4), h5 = f2bf(r5), h6 = f2bf(r6), h7 = f2bf(r7);
            u32x4 hp = {(unsigned int)h0 | ((unsigned int)h1 << 16),
                        (unsigned int)h2 | ((unsigned int)h3 << 16),
                        (unsigned int)h4 | ((unsigned int)h5 << 16),
                        (unsigned int)h6 | ((unsigned int)h7 << 16)};
            unsigned short l0 = f2bf(r0 - bf2f(h0)), l1 = f2bf(r1 - bf2f(h1));
            unsigned short l2 = f2bf(r2 - bf2f(h2)), l3 = f2bf(r3 - bf2f(h3));
            unsigned short l4 = f2bf(r4 - bf2f(h4)), l5 = f2bf(r5 - bf2f(h5));
            unsigned short l6 = f2bf(r6 - bf2f(h6)), l7 = f2bf(r7 - bf2f(h7));
            u32x4 lp = {(unsigned int)l0 | ((unsigned int)l1 << 16),
                        (unsigned int)l2 | ((unsigned int)l3 << 16),
                        (unsigned int)l4 | ((unsigned int)l5 << 16),
                        (unsigned int)l6 | ((unsigned int)l7 << 16)};
            __builtin_nontemporal_store(hp, (u32x4*)&xh_out[(size_t)node * GCN_DIM + cg]);
            __builtin_nontemporal_store(lp, (u32x4*)&xl_out[(size_t)node * GCN_DIM + cg]);
        }
    }
}

extern "C" void kernel_launch(void* const* d_in, const int* in_sizes, int n_in,
                              void* d_out, int out_size, void* d_ws, size_t ws_size,
                              hipStream_t stream) {
    const float* x0    = (const float*)d_in[0];
    const int*   edges = (const int*)d_in[1];   // [2, E] int32: src then dst
    const float* Wall  = (const float*)d_in[2]; // [L, 128, 128]
    const float* Ball  = (const float*)d_in[3]; // [L, 128]
    float* out = (float*)d_out;

    const int n = in_sizes[0] / GCN_DIM;              // 50000
    const int E = in_sizes[1] / 2;                    // 800000
    const int L = in_sizes[2] / (GCN_DIM * GCN_DIM);  // 5

    // workspace layout
    int*   cnt    = (int*)d_ws;                        // n
    float* dinv   = (float*)(cnt + n);                 // n
    int*   offs   = (int*)(dinv + n);                  // n+16
    int*   bsum   = offs + n + 16;                     // 64
    int*   rank   = bsum + 64;                         // E
    unsigned int* edat = (unsigned int*)(rank + E);    // E (4B each)
    unsigned short* h   = (unsigned short*)(edat + E); // n*128 bf16 (slice-major)
    unsigned short* xh  = h  + (size_t)n * GCN_DIM;    // n*128 bf16
    unsigned short* xl  = xh + (size_t)n * GCN_DIM;    // n*128 bf16
    unsigned short* Wfh = xl + (size_t)n * GCN_DIM;    // L*16384 bf16 frag-order
    unsigned short* Wfl = Wfh + (size_t)L * GCN_DIM * GCN_DIM;

    const int* src = edges;
    const int* dst = edges + E;

    int nb_n = (n + 255) / 256;
    int nb_e = (E + 255) / 256;
    int nb_scan = (n + 1023) / 1024;

    hipMemsetAsync(cnt, 0, (size_t)n * sizeof(int), stream);
    count_kernel<<<nb_e, 256, 0, stream>>>(dst, cnt, rank, E);
    scan_part_kernel<<<nb_scan, 256, 0, stream>>>(cnt, offs, bsum, n);
    scan_top_kernel<<<1, 256, 0, stream>>>(bsum, nb_scan);
    scan_add_kernel<<<nb_n, 256, 0, stream>>>(offs, bsum, cnt, dinv, n, E);
    fill_kernel<<<nb_e, 256, 0, stream>>>(src, dst, rank, offs, edat, E);

    int xtotal = n * GCN_DIM;
    split_x_kernel<<<(xtotal / 4 + 255) / 256, 256, 0, stream>>>(x0, xh, xl, xtotal);
    int wtotal = L * GCN_DIM * GCN_DIM;
    wsplit_kernel<<<(wtotal + 255) / 256, 256, 0, stream>>>(Wall, Wfh, Wfl, wtotal);

    int gemm_blocks = (n + 63) / 64;
    int agg_blocks  = ((n + 31) / 32) * 8;  // 32 nodes x 8 slices per block

    for (int l = 0; l < L; l++) {
        gemm_mfma_kernel<<<gemm_blocks, 256, 0, stream>>>(
            xh, xl, Wfh + (size_t)l * GCN_DIM * GCN_DIM, Wfl + (size_t)l * GCN_DIM * GCN_DIM,
            dinv, h, n);
        agg_kernel<<<agg_blocks, 256, 0, stream>>>(
            h, edat, offs, dinv, Ball + (size_t)l * GCN_DIM,
            xh, xl, (l == L - 1) ? out : nullptr, n);
    }
}